// Round 4
// baseline (164.829 us; speedup 1.0000x reference)
//
#include <hip/hip_runtime.h>

#define LL   8192   // sequence length
#define CC   2048   // channels
#define FF   128    // inner dim of g@kernel
#define KK   257    // taps
#define PAD  128    // (KK-1)/2

#define SROWP 328   // synEb row stride (u16): 32 zeros | 257 taps | 31 zeros | 8 pad (164 dw)
#define NT   18     // K-steps of 16 -> covers K in [0,288)
#define NCH  4      // channels per block = waves per block (1 wave : 1 channel)
#define NW   4      // windows (1024 outputs) per block
#define ROWS 1288   // xch row in u16 = 644 dwords == 4 (mod 32 banks) -> conflict-free writes

typedef __bf16 bf16x8 __attribute__((ext_vector_type(8)));
typedef float  f32x16 __attribute__((ext_vector_type(16)));

static __device__ __forceinline__ unsigned short f2bf(float f) {
    unsigned u = __float_as_uint(f);
    u = (u + 0x7fffu + ((u >> 16) & 1u)) >> 16;   // RNE
    return (unsigned short)u;
}

// Build synEb[c][328] bf16: zeros | g[c,:]@kernel[:,k] | zeros (incl. pad), with the
// Yt-row override folded in as a delta kernel (tap=1 at k=128).
__global__ __launch_bounds__(256) void synb_kernel(const float* __restrict__ g,
                                                   const float* __restrict__ kern,
                                                   const int* __restrict__ Yt, int ny,
                                                   unsigned short* __restrict__ synEb) {
    __shared__ int sfl[4];
    const int c0 = blockIdx.x * 4;
    const int t  = threadIdx.x;
    if (t < 4) sfl[t] = 0;
    __syncthreads();
    for (int i = t; i < ny; i += 256) {
        int y = Yt[i];
        #pragma unroll
        for (int ii = 0; ii < 4; ++ii) if (y == c0 + ii) sfl[ii] = 1;
    }
    __syncthreads();
    const float* g0 = g + (size_t)(c0 + 0) * FF;
    const float* g1 = g + (size_t)(c0 + 1) * FF;
    const float* g2 = g + (size_t)(c0 + 2) * FF;
    const float* g3 = g + (size_t)(c0 + 3) * FF;
    const int fl0 = sfl[0], fl1 = sfl[1], fl2 = sfl[2], fl3 = sfl[3];
    for (int p = t; p < SROWP; p += 256) {
        const int kk = p - 32;
        float a0 = 0.f, a1 = 0.f, a2 = 0.f, a3 = 0.f;
        const bool inr = (kk >= 0) && (kk < KK);
        if (inr) {
            #pragma unroll 8
            for (int f = 0; f < FF; ++f) {
                float kv = kern[f * KK + kk];      // coalesced across p
                a0 += kv * g0[f];
                a1 += kv * g1[f];
                a2 += kv * g2[f];
                a3 += kv * g3[f];
            }
        }
        float dlt = (kk == PAD) ? 1.f : 0.f;
        float v0 = inr ? (fl0 ? dlt : a0) : 0.f;
        float v1 = inr ? (fl1 ? dlt : a1) : 0.f;
        float v2 = inr ? (fl2 ? dlt : a2) : 0.f;
        float v3 = inr ? (fl3 ? dlt : a3) : 0.f;
        synEb[(size_t)(c0 + 0) * SROWP + p] = f2bf(v0);
        synEb[(size_t)(c0 + 1) * SROWP + p] = f2bf(v1);
        synEb[(size_t)(c0 + 2) * SROWP + p] = f2bf(v2);
        synEb[(size_t)(c0 + 3) * SROWP + p] = f2bf(v3);
    }
}

// ---- staging helpers (256 threads, 4 channels, float2 = 2ch per lane) ----
// T14 async split: issue-early global->reg, write-late reg->LDS.
static __device__ __forceinline__ void stage_issue(const float* __restrict__ x,
                                                   int W0, int c0, int t,
                                                   float2* ev, float2* ov) {
    #pragma unroll
    for (int k = 0; k < 5; ++k) {
        int pidx = (k << 8) + t;              // [0,1280)
        int ch2  = pidx & 1;                  // channel pair (2 of 4)
        int pp   = pidx >> 1;                 // l-pair index [0,640)
        int lg   = W0 + (pp << 1) - 128;      // global l of even element
        const float* sp = x + (size_t)lg * CC + c0 + (ch2 << 1);
        float2 a = make_float2(0.f, 0.f);
        float2 b = make_float2(0.f, 0.f);
        if ((unsigned)lg       < (unsigned)LL) a = *(const float2*)sp;
        if ((unsigned)(lg + 1) < (unsigned)LL) b = *(const float2*)(sp + CC);
        ev[k] = a; ov[k] = b;
    }
}

static __device__ __forceinline__ void stage_write(unsigned short (*buf)[ROWS], int t,
                                                   const float2* ev, const float2* ov) {
    #pragma unroll
    for (int k = 0; k < 5; ++k) {
        int pidx = (k << 8) + t;
        int ch2  = pidx & 1;
        int pp   = pidx >> 1;
        int gq   = pp >> 2;                   // granule (8 u16)
        int gp   = gq ^ ((gq >> 3) & 7);      // XOR swizzle (verified layout)
        int dw   = (gp << 2) | (pp & 3);      // dword slot within row
        const float* pe = (const float*)&ev[k];
        const float* po = (const float*)&ov[k];
        #pragma unroll
        for (int c2 = 0; c2 < 2; ++c2) {
            unsigned val = (unsigned)f2bf(pe[c2]) | ((unsigned)f2bf(po[c2]) << 16);
            ((unsigned*)buf[(ch2 << 1) + c2])[dw] = val;
        }
    }
}

// Fused transpose + depthwise Toeplitz-MFMA conv, occupancy-first shape.
// Block: 256 threads / 4 waves; 1 wave = 1 channel; 4 windows of 1024 outputs.
// B-fragments come from a parity-duplicated LDS copy of syn (copy0[i]=row[i],
// copy1[i]=row[i+1]): each lane's fragment is a DIRECT 4-dword read at
// dword e0+8m of copy_p (p = lane-parity, constant) -- no funnel shifts, no
// 72-VGPR bfrag array. Frees registers for 4 waves/SIMD; 25.9 KB LDS fits
// 4 blocks/CU; grid 1024 = exactly 4 blocks/CU, zero tail -> ~16 waves/CU.
__global__ __launch_bounds__(256, 4) void fused_conv(const float* __restrict__ x,
                                                     const unsigned short* __restrict__ synEb,
                                                     float* __restrict__ out) {
    __shared__ alignas(16) unsigned short xch[2][NCH][ROWS];   // 20,608 B
    __shared__ alignas(16) unsigned short synD[NCH][2][SROWP]; //  5,248 B
    const int t = threadIdx.x;

    // XCD-slab mapping: dispatch d lands on XCD d%8 (round-robin). Give XCD r
    // the contiguous channel slab [256r, 256r+256) (64 cg x 2 l-halves = its
    // full 128 resident blocks), so every 128B x-line (32 ch) is fetched once
    // per XCD and shared in L2 by co-resident blocks. Bijective on [0,1024).
    const int d  = blockIdx.x;                 // [0,1024)
    const int cg = ((d & 7) << 6) | (d >> 4);  // [0,512)
    const int c0 = cg << 2;
    const int L0 = ((d >> 3) & 1) << 12;       // l-half base

    const int ci = t >> 6;                     // wave id = channel index [0,4)
    const int ln = t & 63;
    const int j = ln & 31, q = ln >> 5;
    const int gb = (j << 2) + q;               // A granule base
    // B fragment geometry: B.u16[r] = row[ib + 16m + r], ib = 8q - j + 32.
    const int ib   = (q << 3) - j + 32;        // in [1,40]
    const int ppar = ib & 1;                   // parity (constant over m)
    const int e0   = (ib - ppar) >> 1;         // dword base in copy_ppar, [0,20]

    // ---- issue window-0 x loads first: HBM latency hides under synD build ----
    float2 ev[5], ov[5];
    stage_issue(x, L0, c0, t, ev, ov);

    // ---- build parity-dup syn copies: synD[c][0][i]=row[i], synD[c][1][i]=row[i+1] ----
    for (int u = t; u < NCH * 2 * SROWP; u += 256) {
        int ci2 = u / (2 * SROWP);
        int rem = u - ci2 * (2 * SROWP);
        int p   = (rem >= SROWP) ? 1 : 0;
        int idx = rem - (p ? SROWP : 0);
        int src = idx + p;
        if (src > SROWP - 1) src = SROWP - 1;  // row[327]=0 == conceptual row[328]
        synD[ci2][p][idx] = synEb[(size_t)(c0 + ci2) * SROWP + src];
    }

    // ---- prologue: write window 0 into buf 0 ----
    stage_write(xch[0], t, ev, ov);
    __syncthreads();

    // per-lane B base pointer (dword units); fragment m = bp[8m .. 8m+3]
    const unsigned* bp = (const unsigned*)(synD[ci][ppar]) + e0;

    for (int w = 0; w < NW; ++w) {
        const int cur = w & 1;
        const int W0  = L0 + (w << 10);
        // issue next window's loads BEFORE compute (latency hides under MFMA+stores)
        if (w + 1 < NW) stage_issue(x, W0 + 1024, c0, t, ev, ov);

        // ---- compute: 18 x {ds_read_b128 A, 4-dword B read, MFMA} ----
        const char* xrow = (const char*)xch[cur][ci];
        f32x16 acc;
        #pragma unroll
        for (int r = 0; r < 16; ++r) acc[r] = 0.f;
        #pragma unroll
        for (int m = 0; m < NT; ++m) {
            int gq2 = gb + (m << 1);
            int gp2 = gq2 ^ ((gq2 >> 3) & 7);
            union { int4 i4; bf16x8 v; } A;
            A.i4 = *(const int4*)(xrow + (gp2 << 4));
            union { unsigned dd[4]; bf16x8 v; } B;
            B.dd[0] = bp[(m << 3) + 0];
            B.dd[1] = bp[(m << 3) + 1];
            B.dd[2] = bp[(m << 3) + 2];
            B.dd[3] = bp[(m << 3) + 3];
            acc = __builtin_amdgcn_mfma_f32_32x32x16_bf16(A.v, B.v, acc, 0, 0, 0);
        }
        // ---- store: D col=lane&31, row=(r&3)+8*(r>>2)+4q ----
        float* o = out + (size_t)(c0 + ci) * LL + W0 + j;
        #pragma unroll
        for (int r = 0; r < 16; ++r) {
            int row = (r & 3) + ((r >> 2) << 3) + (q << 2);
            o[row << 5] = acc[r];              // 2 x 128B segments per instr
        }
        __syncthreads();                       // all waves done reading xch[cur]
        // write-late: staged regs -> other buffer (vmcnt satisfied under compute)
        if (w + 1 < NW) stage_write(xch[cur ^ 1], t, ev, ov);
        __syncthreads();
    }
}

// ------------------------------------------------------------------- launch
extern "C" void kernel_launch(void* const* d_in, const int* in_sizes, int n_in,
                              void* d_out, int out_size, void* d_ws, size_t ws_size,
                              hipStream_t stream) {
    const float* x    = (const float*)d_in[0];
    const int*   Yt   = (const int*)  d_in[1];
    const float* g    = (const float*)d_in[2];
    const float* kern = (const float*)d_in[3];
    float* out = (float*)d_out;
    const int ny = in_sizes[1];

    unsigned short* synEb = (unsigned short*)d_ws;   // 2048*328*2 = 1.34 MB

    synb_kernel<<<CC / 4, 256, 0, stream>>>(g, kern, Yt, ny, synEb);
    fused_conv<<<1024, 256, 0, stream>>>(x, synEb, out);
}

// Round 5
// 153.048 us; speedup vs baseline: 1.0770x; 1.0770x over previous
//
#include <hip/hip_runtime.h>

#define LL   8192   // sequence length
#define CC   2048   // channels
#define FF   128    // inner dim of g@kernel
#define KK   257    // taps
#define PAD  128    // (KK-1)/2

#define SROWP 328   // synEb row stride (u16): 32 zeros | 257 taps | 31 zeros | 8 pad (164 dw)
#define NT   9      // K-steps of 32 (16x16x32 MFMA) -> covers shifted-tap idx [17,319]
#define NCH  4      // channels per block = waves per block (1 wave : 1 channel)
#define NW   4      // windows (1024 outputs) per block
#define ROWS 1352   // xch row u16: 169 granules (reads reach granule 167); 676 dw == 4 (mod 32)

typedef __bf16 bf16x8 __attribute__((ext_vector_type(8)));
typedef float  f32x4  __attribute__((ext_vector_type(4)));

static __device__ __forceinline__ unsigned short f2bf(float f) {
    unsigned u = __float_as_uint(f);
    u = (u + 0x7fffu + ((u >> 16) & 1u)) >> 16;   // RNE
    return (unsigned short)u;
}

// Build synEb[c][328] bf16: zeros | g[c,:]@kernel[:,k] | zeros (incl. pad), with the
// Yt-row override folded in as a delta kernel (tap=1 at k=128).
__global__ __launch_bounds__(256) void synb_kernel(const float* __restrict__ g,
                                                   const float* __restrict__ kern,
                                                   const int* __restrict__ Yt, int ny,
                                                   unsigned short* __restrict__ synEb) {
    __shared__ int sfl[4];
    const int c0 = blockIdx.x * 4;
    const int t  = threadIdx.x;
    if (t < 4) sfl[t] = 0;
    __syncthreads();
    for (int i = t; i < ny; i += 256) {
        int y = Yt[i];
        #pragma unroll
        for (int ii = 0; ii < 4; ++ii) if (y == c0 + ii) sfl[ii] = 1;
    }
    __syncthreads();
    const float* g0 = g + (size_t)(c0 + 0) * FF;
    const float* g1 = g + (size_t)(c0 + 1) * FF;
    const float* g2 = g + (size_t)(c0 + 2) * FF;
    const float* g3 = g + (size_t)(c0 + 3) * FF;
    const int fl0 = sfl[0], fl1 = sfl[1], fl2 = sfl[2], fl3 = sfl[3];
    for (int p = t; p < SROWP; p += 256) {
        const int kk = p - 32;
        float a0 = 0.f, a1 = 0.f, a2 = 0.f, a3 = 0.f;
        const bool inr = (kk >= 0) && (kk < KK);
        if (inr) {
            #pragma unroll 8
            for (int f = 0; f < FF; ++f) {
                float kv = kern[f * KK + kk];      // coalesced across p
                a0 += kv * g0[f];
                a1 += kv * g1[f];
                a2 += kv * g2[f];
                a3 += kv * g3[f];
            }
        }
        float dlt = (kk == PAD) ? 1.f : 0.f;
        float v0 = inr ? (fl0 ? dlt : a0) : 0.f;
        float v1 = inr ? (fl1 ? dlt : a1) : 0.f;
        float v2 = inr ? (fl2 ? dlt : a2) : 0.f;
        float v3 = inr ? (fl3 ? dlt : a3) : 0.f;
        synEb[(size_t)(c0 + 0) * SROWP + p] = f2bf(v0);
        synEb[(size_t)(c0 + 1) * SROWP + p] = f2bf(v1);
        synEb[(size_t)(c0 + 2) * SROWP + p] = f2bf(v2);
        synEb[(size_t)(c0 + 3) * SROWP + p] = f2bf(v3);
    }
}

// ---- stage one window: x[(l,c) fp32] -> bf16 LDS rows, XOR-granule-swizzled ----
// One float4 covers all 4 block channels; lanes = distinct l rows (16B segments,
// L2-served via XCD slab mapping). 672 l-pairs = 168 granules: covers the MFMA
// over-read tail (granules 160..167, which pair with zero taps) with finite data.
static __device__ __forceinline__ void stage(const float* __restrict__ x,
                                             unsigned short (*buf)[ROWS],
                                             int W0, int c0, int t) {
    #pragma unroll
    for (int k = 0; k < 3; ++k) {
        int pp = (k << 8) + t;                // l-pair index [0,672)
        if (pp < 672) {
            int lg = W0 + (pp << 1) - 128;    // global l of even element
            const float* sp = x + (size_t)lg * CC + c0;
            float4 a = make_float4(0.f, 0.f, 0.f, 0.f);
            float4 b = make_float4(0.f, 0.f, 0.f, 0.f);
            if ((unsigned)lg       < (unsigned)LL) a = *(const float4*)sp;
            if ((unsigned)(lg + 1) < (unsigned)LL) b = *(const float4*)(sp + CC);
            int gq = pp >> 2;                 // granule (8 u16)
            int gp = gq ^ ((gq >> 3) & 7);    // XOR swizzle (verified layout)
            int dw = (gp << 2) | (pp & 3);    // dword slot within row
            const float* pe = (const float*)&a;
            const float* po = (const float*)&b;
            #pragma unroll
            for (int c2 = 0; c2 < 4; ++c2) {  // row stride 676 dw == 4 mod 32: 4 banks apart
                unsigned val = (unsigned)f2bf(pe[c2]) | ((unsigned)f2bf(po[c2]) << 16);
                ((unsigned*)buf[c2])[dw] = val;
            }
        }
    }
}

// Fused transpose + depthwise Toeplitz conv via mfma_f32_16x16x32_bf16.
// The shape switch (32x32x16 -> 16x16x32) halves the hoisted B-fragment cost
// (NT=9 x 4dw = 36 VGPR vs 72), fitting ~120 VGPR -> 4 waves/SIMD. Block =
// 4 waves = 4 channels x 4 windows; grid 1024 = 4 blocks/CU, zero tail, 16
// waves/CU. Inner loop: m-outer/s-inner -> 4 independent acc chains (ILP 4),
// 36 x {swizzled ds_read_b128 + MFMA} per window, ONE barrier per window
// (double-buffered xch).
// Mapping (derived same way as the harness-verified 32x32 version):
//   D[row][col] = out[c, T0 + 16row + col], col=lane&15=n, row=4*(lane>>4)+r
//   B_m[kap][n] = row16[32m + 8q' + r - n + 32]   (q'=lane>>4, kap=8q'+r)
//   A_m[i][kap] = x[T0 + 16i + 32m + 8q' + r - 128], i=lane&15 -> granule
//                 g = 32s + 2i + q' + 4m in the swizzled xch row.
// Coverage: sum_u x[T0+16i+u-128]*syn[u-n], u=32m+8q'+r in [0,288) covers all
// taps k in [0,257) for every n<=15; row16 idx in [17,319], zeros outside taps.
__global__ __launch_bounds__(256, 4) void fused_conv(const float* __restrict__ x,
                                                     const unsigned short* __restrict__ synEb,
                                                     float* __restrict__ out) {
    __shared__ alignas(16) unsigned short xch[2][NCH][ROWS];   // 21,632 B
    __shared__ alignas(16) unsigned short synD[NCH][2][SROWP]; //  5,248 B
    const int t = threadIdx.x;

    // XCD slab mapping: dispatch d -> XCD d%8 (round-robin). XCD r owns channels
    // [256r, 256r+256): every 128B x-line (32 ch) is fetched once per XCD and
    // shared in L2 by its co-resident blocks. Bijective on [0,1024).
    const int d  = blockIdx.x;                 // [0,1024)
    const int cg = ((d & 7) << 6) | (d >> 4);  // [0,512)
    const int c0 = cg << 2;
    const int L0 = ((d >> 3) & 1) << 12;       // l-half base

    const int ci = t >> 6;                     // wave id = channel index [0,4)
    const int ln = t & 63;
    const int n  = ln & 15, q4 = ln >> 4;      // B col / A k-group
    const int gbase = (n << 1) + q4;           // A granule base (i = n)
    // B geometry: u16 idx = ib + 32m, ib = 8q' - n + 32 in [17,56]
    const int ib  = (q4 << 3) - n + 32;
    const int par = ib & 1;                    // parity (constant over m)
    const int e0  = (ib - par) >> 1;           // dword base in parity-copy, [8,28]

    // ---- build parity-dup syn copies: synD[c][p][t16] = row16[t16 + p] ----
    for (int u = t; u < NCH * 2 * SROWP; u += 256) {
        int ci2 = u / (2 * SROWP);
        int rem = u - ci2 * (2 * SROWP);
        int p   = (rem >= SROWP) ? 1 : 0;
        int idx = rem - (p ? SROWP : 0);
        int src = idx + p;
        if (src > SROWP - 1) src = SROWP - 1;  // row16[>=288] are zeros
        synD[ci2][p][idx] = synEb[(size_t)(c0 + ci2) * SROWP + src];
    }
    // ---- stage window 0 ----
    stage(x, xch[0], L0, c0, t);
    __syncthreads();

    // ---- hoist B fragments ONCE (window-invariant): 9 x 4 dw = 36 VGPR ----
    bf16x8 bfrag[NT];
    {
        const unsigned* bp = (const unsigned*)(synD[ci][par]) + e0;
        #pragma unroll
        for (int m = 0; m < NT; ++m) {         // max dword = 28 + 128 + 3 = 159 < 164
            union { unsigned dd[4]; bf16x8 v; } B;
            B.dd[0] = bp[(m << 4) + 0];
            B.dd[1] = bp[(m << 4) + 1];
            B.dd[2] = bp[(m << 4) + 2];
            B.dd[3] = bp[(m << 4) + 3];
            bfrag[m] = B.v;
        }
    }

    for (int w = 0; w < NW; ++w) {
        const int cur = w & 1;
        const int W0  = L0 + (w << 10);
        const char* xrow = (const char*)xch[cur][ci];

        f32x4 acc[4];
        #pragma unroll
        for (int s = 0; s < 4; ++s) acc[s] = (f32x4){0.f, 0.f, 0.f, 0.f};
        #pragma unroll
        for (int m = 0; m < NT; ++m) {
            #pragma unroll
            for (int s = 0; s < 4; ++s) {      // 4 independent chains
                int g  = gbase + (s << 5) + (m << 2);   // <= 161
                int gp = g ^ ((g >> 3) & 7);            // <= 167 (in-row: 169 granules)
                union { int4 i4; bf16x8 v; } A;
                A.i4 = *(const int4*)(xrow + (gp << 4));
                acc[s] = __builtin_amdgcn_mfma_f32_16x16x32_bf16(A.v, bfrag[m], acc[s], 0, 0, 0);
            }
        }
        // ---- store: l = W0 + 256s + 64q4 + 16r + n -> 4 x 64B segments/instr ----
        float* o = out + (size_t)(c0 + ci) * LL + W0 + (q4 << 6) + n;
        #pragma unroll
        for (int s = 0; s < 4; ++s) {
            #pragma unroll
            for (int r = 0; r < 4; ++r) o[(s << 8) + (r << 4)] = acc[s][r];
        }
        // stage next window into the other buffer; latency hidden by 16 waves/CU
        if (w + 1 < NW) stage(x, xch[cur ^ 1], W0 + 1024, c0, t);
        __syncthreads();
    }
}

// ------------------------------------------------------------------- launch
extern "C" void kernel_launch(void* const* d_in, const int* in_sizes, int n_in,
                              void* d_out, int out_size, void* d_ws, size_t ws_size,
                              hipStream_t stream) {
    const float* x    = (const float*)d_in[0];
    const int*   Yt   = (const int*)  d_in[1];
    const float* g    = (const float*)d_in[2];
    const float* kern = (const float*)d_in[3];
    float* out = (float*)d_out;
    const int ny = in_sizes[1];

    unsigned short* synEb = (unsigned short*)d_ws;   // 2048*328*2 = 1.34 MB

    synb_kernel<<<CC / 4, 256, 0, stream>>>(g, kern, Yt, ny, synEb);
    fused_conv<<<1024, 256, 0, stream>>>(x, synEb, out);
}